// Round 5
// baseline (210.233 us; speedup 1.0000x reference)
//
#include <hip/hip_runtime.h>

// CompositeLoss: fused masked reduction over (2,3,128,128,128).
// R5: channel-split threads. Thread owns (c,b,d,h,w4): 3*2^20 threads.
// Per-thread: 9 float4 + 3 scalar loads, ALL independent -> issued in one
// burst (latency-bound regime: maximize loads-in-flight x waves/SIMD).
// Mask sums acc[0..3] are triple-counted across c -- exactly the *C=3
// denominator the reference uses, so no correction needed.
// 13 partial sums (padded to 16 per block row in d_ws):
//  0:3M 1:3Mx(d) 2:3My(h) 3:3Mz(w)  4:Smae 5:Smse 6:Sbg
//  7:Sgx 8:Sgy 9:Sgz  10:Stx 11:Sty 12:Stz
#define NACC 13
#define NPAD 16
#define NBLOCKS 12288   // 3*2^20 threads / 256

__device__ __forceinline__ float4 ld4(const float* p) {
    return *reinterpret_cast<const float4*>(p);
}

__global__ __launch_bounds__(256) void loss_main(
    const float* __restrict__ pred, const float* __restrict__ target,
    const float* __restrict__ mask, float* __restrict__ partials)
{
    float acc[NACC];
#pragma unroll
    for (int k = 0; k < NACC; ++k) acc[k] = 0.f;

    const float4 z4 = make_float4(0.f, 0.f, 0.f, 0.f);

    const int g  = blockIdx.x * 256 + threadIdx.x;
    const int w4 = g & 31;
    const int h  = (g >> 5) & 127;
    const int d  = (g >> 12) & 127;
    const int bc = g >> 19;        // 0..5 = c*2 + b
    const int b  = bc & 1;
    const int c  = bc >> 1;
    const int w  = w4 << 2;
    const int sp = d * 16384 + h * 128 + w;
    const int mb = b * 2097152 + sp;             // mask index
    const int pb = (b * 3 + c) * 2097152 + sp;   // pred/target index
    const bool hw = w4 < 31, hh = h < 127, hd = d < 127;

    // ---- all 12 loads issued up front, no inter-dependencies ----
    const float4 m0  = ld4(mask + mb);
    const float4 mh  = hh ? ld4(mask + mb + 128)   : z4;
    const float4 md  = hd ? ld4(mask + mb + 16384) : z4;
    const float4 p0  = ld4(pred + pb);
    const float4 t0  = ld4(target + pb);
    const float4 ph  = hh ? ld4(pred + pb + 128)     : z4;
    const float4 th  = hh ? ld4(target + pb + 128)   : z4;
    const float4 pd  = hd ? ld4(pred + pb + 16384)   : z4;
    const float4 td  = hd ? ld4(target + pb + 16384) : z4;
    float m4w = 0.f, p4 = 0.f, t4 = 0.f;
    if (hw) { m4w = mask[mb + 4]; p4 = pred[pb + 4]; t4 = target[pb + 4]; }

    // pairwise mins (binary mask -> AND); zero-filled neighbors kill OOB terms
    const float mz0 = fminf(m0.x, m0.y), mz1 = fminf(m0.y, m0.z),
                mz2 = fminf(m0.z, m0.w), mz3 = fminf(m0.w, m4w);
    const float my0 = fminf(m0.x, mh.x), my1 = fminf(m0.y, mh.y),
                my2 = fminf(m0.z, mh.z), my3 = fminf(m0.w, mh.w);
    const float mx0 = fminf(m0.x, md.x), mx1 = fminf(m0.y, md.y),
                mx2 = fminf(m0.z, md.z), mx3 = fminf(m0.w, md.w);

    acc[0] = m0.x + m0.y + m0.z + m0.w;   // triple-counted = 3*M, as needed
    acc[1] = mx0 + mx1 + mx2 + mx3;
    acc[2] = my0 + my1 + my2 + my3;
    acc[3] = mz0 + mz1 + mz2 + mz3;

    const float e0x = p0.x - t0.x, e0y = p0.y - t0.y,
                e0z = p0.z - t0.z, e0w = p0.w - t0.w;
    const float e4  = p4 - t4;

    acc[4] = fabsf(e0x)*m0.x + fabsf(e0y)*m0.y
           + fabsf(e0z)*m0.z + fabsf(e0w)*m0.w;
    acc[5] = e0x*e0x*m0.x + e0y*e0y*m0.y
           + e0z*e0z*m0.z + e0w*e0w*m0.w;
    acc[6] = fabsf(p0.x)*(1.f-m0.x) + fabsf(p0.y)*(1.f-m0.y)
           + fabsf(p0.z)*(1.f-m0.z) + fabsf(p0.w)*(1.f-m0.w);

    // W direction (reference dz)
    acc[9]  = fabsf(e0y-e0x)*mz0 + fabsf(e0z-e0y)*mz1
            + fabsf(e0w-e0z)*mz2 + fabsf(e4 -e0w)*mz3;
    acc[12] = fabsf(p0.y-p0.x)*mz0 + fabsf(p0.z-p0.y)*mz1
            + fabsf(p0.w-p0.z)*mz2 + fabsf(p4  -p0.w)*mz3;

    // H direction (reference dy)
    acc[8]  = fabsf((ph.x-th.x)-e0x)*my0 + fabsf((ph.y-th.y)-e0y)*my1
            + fabsf((ph.z-th.z)-e0z)*my2 + fabsf((ph.w-th.w)-e0w)*my3;
    acc[11] = fabsf(ph.x-p0.x)*my0 + fabsf(ph.y-p0.y)*my1
            + fabsf(ph.z-p0.z)*my2 + fabsf(ph.w-p0.w)*my3;

    // D direction (reference dx)
    acc[7]  = fabsf((pd.x-td.x)-e0x)*mx0 + fabsf((pd.y-td.y)-e0y)*mx1
            + fabsf((pd.z-td.z)-e0z)*mx2 + fabsf((pd.w-td.w)-e0w)*mx3;
    acc[10] = fabsf(pd.x-p0.x)*mx0 + fabsf(pd.y-p0.y)*mx1
            + fabsf(pd.z-p0.z)*mx2 + fabsf(pd.w-p0.w)*mx3;

    // wave (64) shuffle reduce -> LDS -> padded per-block row [block][16]
    const int lane = threadIdx.x & 63;
    const int wave = threadIdx.x >> 6;
    __shared__ float red[4][NACC];
#pragma unroll
    for (int k = 0; k < NACC; ++k) {
        float v = acc[k];
        for (int o = 32; o > 0; o >>= 1) v += __shfl_down(v, o, 64);
        if (lane == 0) red[wave][k] = v;
    }
    __syncthreads();
    if (threadIdx.x < NPAD) {
        const int k = threadIdx.x;
        const float v = (k < NACC)
            ? red[0][k] + red[1][k] + red[2][k] + red[3][k] : 0.f;
        partials[blockIdx.x * NPAD + k] = v;  // d_ws is poisoned: write all 16
    }
}

__global__ __launch_bounds__(1024) void loss_final(
    const float* __restrict__ partials, float* __restrict__ out)
{
    // 1024 threads; thread t owns rows t + i*1024, i=0..11.
    // 48 independent float4 loads per thread -> latency fully overlapped.
    float4 a0 = make_float4(0, 0, 0, 0), a1 = a0, a2 = a0, a3 = a0;
#pragma unroll
    for (int i = 0; i < 12; ++i) {
        const float* row = partials + (threadIdx.x + (i << 10)) * NPAD;
        const float4 r0 = ld4(row);     const float4 r1 = ld4(row + 4);
        const float4 r2 = ld4(row + 8); const float4 r3 = ld4(row + 12);
        a0.x += r0.x; a0.y += r0.y; a0.z += r0.z; a0.w += r0.w;
        a1.x += r1.x; a1.y += r1.y; a1.z += r1.z; a1.w += r1.w;
        a2.x += r2.x; a2.y += r2.y; a2.z += r2.z; a2.w += r2.w;
        a3.x += r3.x; a3.y += r3.y; a3.z += r3.z; a3.w += r3.w;
    }
    float acc[NPAD] = {a0.x, a0.y, a0.z, a0.w, a1.x, a1.y, a1.z, a1.w,
                       a2.x, a2.y, a2.z, a2.w, a3.x, a3.y, a3.z, a3.w};

    const int lane = threadIdx.x & 63;
    const int wave = threadIdx.x >> 6;
    __shared__ float red[16][NPAD];
#pragma unroll
    for (int k = 0; k < NPAD; ++k) {
        float v = acc[k];
        for (int o = 32; o > 0; o >>= 1) v += __shfl_down(v, o, 64);
        if (lane == 0) red[wave][k] = v;
    }
    __syncthreads();
    if (threadIdx.x == 0) {
        float a[NACC];
#pragma unroll
        for (int k = 0; k < NACC; ++k) {
            float v = 0.f;
#pragma unroll
            for (int wv = 0; wv < 16; ++wv) v += red[wv][k];
            a[k] = v;
        }
        const float EPS = 1e-8f;
        // a[0..3] are already 3*M, 3*Mx, 3*My, 3*Mz (triple-counted)
        float loss = (a[4] + a[5]) / (a[0] + EPS);      // W_MAE=1, W_MSE=1
        loss += 0.1f   * (a[7] / (a[1] + EPS) + a[8] / (a[2] + EPS)
                        + a[9] / (a[3] + EPS));
        loss += 0.002f * (a[10] / (a[1] + EPS) + a[11] / (a[2] + EPS)
                        + a[12] / (a[3] + EPS));
        const float inv3 = 12582912.f - a[0];  // 3*(B*D*H*W) - 3*M
        loss += 0.15f * a[6] / (inv3 + EPS);
        out[0] = loss;
    }
}

extern "C" void kernel_launch(void* const* d_in, const int* in_sizes, int n_in,
                              void* d_out, int out_size, void* d_ws, size_t ws_size,
                              hipStream_t stream) {
    const float* pred   = (const float*)d_in[0];
    const float* target = (const float*)d_in[1];
    const float* mask   = (const float*)d_in[2];
    float* out      = (float*)d_out;
    float* partials = (float*)d_ws;  // NBLOCKS * NPAD floats = 768 KiB

    loss_main<<<NBLOCKS, 256, 0, stream>>>(pred, target, mask, partials);
    loss_final<<<1, 1024, 0, stream>>>(partials, out);
}

// Round 6
// 157.712 us; speedup vs baseline: 1.3330x; 1.3330x over previous
//
#include <hip/hip_runtime.h>

// CompositeLoss: fused masked reduction over (2,3,128,128,128).
// R6: keep R5's channel-split main (max per-thread MLP, low VGPR) but fix the
// tail with a two-level reduction tree: 12288-row partials are reduced by 48
// workgroups (one row per thread, 4 independent float4 loads -> 48 CUs of
// MLP instead of 1), then a single wave folds 48 rows + scalar epilogue.
// Mask sums acc[0..3] are triple-counted across c == the *C=3 denominator.
// 13 partial sums (padded to 16 per block row in d_ws):
//  0:3M 1:3Mx(d) 2:3My(h) 3:3Mz(w)  4:Smae 5:Smse 6:Sbg
//  7:Sgx 8:Sgy 9:Sgz  10:Stx 11:Sty 12:Stz
#define NACC 13
#define NPAD 16
#define NBLOCKS 12288   // 3*2^20 threads / 256
#define NMID 48         // 12288 / 256

__device__ __forceinline__ float4 ld4(const float* p) {
    return *reinterpret_cast<const float4*>(p);
}

__global__ __launch_bounds__(256) void loss_main(
    const float* __restrict__ pred, const float* __restrict__ target,
    const float* __restrict__ mask, float* __restrict__ partials)
{
    float acc[NACC];
#pragma unroll
    for (int k = 0; k < NACC; ++k) acc[k] = 0.f;

    const float4 z4 = make_float4(0.f, 0.f, 0.f, 0.f);

    const int g  = blockIdx.x * 256 + threadIdx.x;
    const int w4 = g & 31;
    const int h  = (g >> 5) & 127;
    const int d  = (g >> 12) & 127;
    const int bc = g >> 19;        // 0..5 = c*2 + b
    const int b  = bc & 1;
    const int c  = bc >> 1;
    const int w  = w4 << 2;
    const int sp = d * 16384 + h * 128 + w;
    const int mb = b * 2097152 + sp;             // mask index
    const int pb = (b * 3 + c) * 2097152 + sp;   // pred/target index
    const bool hw = w4 < 31, hh = h < 127, hd = d < 127;

    // ---- all 12 loads issued up front, no inter-dependencies ----
    const float4 m0  = ld4(mask + mb);
    const float4 mh  = hh ? ld4(mask + mb + 128)   : z4;
    const float4 md  = hd ? ld4(mask + mb + 16384) : z4;
    const float4 p0  = ld4(pred + pb);
    const float4 t0  = ld4(target + pb);
    const float4 ph  = hh ? ld4(pred + pb + 128)     : z4;
    const float4 th  = hh ? ld4(target + pb + 128)   : z4;
    const float4 pd  = hd ? ld4(pred + pb + 16384)   : z4;
    const float4 td  = hd ? ld4(target + pb + 16384) : z4;
    float m4w = 0.f, p4 = 0.f, t4 = 0.f;
    if (hw) { m4w = mask[mb + 4]; p4 = pred[pb + 4]; t4 = target[pb + 4]; }

    // pairwise mins (binary mask -> AND); zero-filled neighbors kill OOB terms
    const float mz0 = fminf(m0.x, m0.y), mz1 = fminf(m0.y, m0.z),
                mz2 = fminf(m0.z, m0.w), mz3 = fminf(m0.w, m4w);
    const float my0 = fminf(m0.x, mh.x), my1 = fminf(m0.y, mh.y),
                my2 = fminf(m0.z, mh.z), my3 = fminf(m0.w, mh.w);
    const float mx0 = fminf(m0.x, md.x), mx1 = fminf(m0.y, md.y),
                mx2 = fminf(m0.z, md.z), mx3 = fminf(m0.w, md.w);

    acc[0] = m0.x + m0.y + m0.z + m0.w;   // triple-counted = 3*M, as needed
    acc[1] = mx0 + mx1 + mx2 + mx3;
    acc[2] = my0 + my1 + my2 + my3;
    acc[3] = mz0 + mz1 + mz2 + mz3;

    const float e0x = p0.x - t0.x, e0y = p0.y - t0.y,
                e0z = p0.z - t0.z, e0w = p0.w - t0.w;
    const float e4  = p4 - t4;

    acc[4] = fabsf(e0x)*m0.x + fabsf(e0y)*m0.y
           + fabsf(e0z)*m0.z + fabsf(e0w)*m0.w;
    acc[5] = e0x*e0x*m0.x + e0y*e0y*m0.y
           + e0z*e0z*m0.z + e0w*e0w*m0.w;
    acc[6] = fabsf(p0.x)*(1.f-m0.x) + fabsf(p0.y)*(1.f-m0.y)
           + fabsf(p0.z)*(1.f-m0.z) + fabsf(p0.w)*(1.f-m0.w);

    // W direction (reference dz)
    acc[9]  = fabsf(e0y-e0x)*mz0 + fabsf(e0z-e0y)*mz1
            + fabsf(e0w-e0z)*mz2 + fabsf(e4 -e0w)*mz3;
    acc[12] = fabsf(p0.y-p0.x)*mz0 + fabsf(p0.z-p0.y)*mz1
            + fabsf(p0.w-p0.z)*mz2 + fabsf(p4  -p0.w)*mz3;

    // H direction (reference dy)
    acc[8]  = fabsf((ph.x-th.x)-e0x)*my0 + fabsf((ph.y-th.y)-e0y)*my1
            + fabsf((ph.z-th.z)-e0z)*my2 + fabsf((ph.w-th.w)-e0w)*my3;
    acc[11] = fabsf(ph.x-p0.x)*my0 + fabsf(ph.y-p0.y)*my1
            + fabsf(ph.z-p0.z)*my2 + fabsf(ph.w-p0.w)*my3;

    // D direction (reference dx)
    acc[7]  = fabsf((pd.x-td.x)-e0x)*mx0 + fabsf((pd.y-td.y)-e0y)*mx1
            + fabsf((pd.z-td.z)-e0z)*mx2 + fabsf((pd.w-td.w)-e0w)*mx3;
    acc[10] = fabsf(pd.x-p0.x)*mx0 + fabsf(pd.y-p0.y)*mx1
            + fabsf(pd.z-p0.z)*mx2 + fabsf(pd.w-p0.w)*mx3;

    // wave (64) shuffle reduce -> LDS -> padded per-block row [block][16]
    const int lane = threadIdx.x & 63;
    const int wave = threadIdx.x >> 6;
    __shared__ float red[4][NACC];
#pragma unroll
    for (int k = 0; k < NACC; ++k) {
        float v = acc[k];
        for (int o = 32; o > 0; o >>= 1) v += __shfl_down(v, o, 64);
        if (lane == 0) red[wave][k] = v;
    }
    __syncthreads();
    if (threadIdx.x < NPAD) {
        const int k = threadIdx.x;
        const float v = (k < NACC)
            ? red[0][k] + red[1][k] + red[2][k] + red[3][k] : 0.f;
        partials[blockIdx.x * NPAD + k] = v;  // d_ws is poisoned: write all 16
    }
}

// Level 1: 48 blocks x 256 threads; thread r reads row r (4 independent
// float4), block-reduces 256 rows -> 1 row. Spreads the latency-bound
// partials read across 48 CUs.
__global__ __launch_bounds__(256) void loss_mid(
    const float* __restrict__ partials, float* __restrict__ mid)
{
    const int r = blockIdx.x * 256 + threadIdx.x;   // exactly covers 12288
    const float* row = partials + r * NPAD;
    const float4 r0 = ld4(row);     const float4 r1 = ld4(row + 4);
    const float4 r2 = ld4(row + 8); const float4 r3 = ld4(row + 12);
    float acc[NPAD] = {r0.x, r0.y, r0.z, r0.w, r1.x, r1.y, r1.z, r1.w,
                       r2.x, r2.y, r2.z, r2.w, r3.x, r3.y, r3.z, r3.w};

    const int lane = threadIdx.x & 63;
    const int wave = threadIdx.x >> 6;
    __shared__ float red[4][NPAD];
#pragma unroll
    for (int k = 0; k < NPAD; ++k) {
        float v = acc[k];
        for (int o = 32; o > 0; o >>= 1) v += __shfl_down(v, o, 64);
        if (lane == 0) red[wave][k] = v;
    }
    __syncthreads();
    if (threadIdx.x < NPAD) {
        const int k = threadIdx.x;
        mid[blockIdx.x * NPAD + k] =
            red[0][k] + red[1][k] + red[2][k] + red[3][k];
    }
}

// Level 2: one wave; lane l reads mid row l (48 rows), shuffle-reduce,
// lane 0 does the scalar epilogue.
__global__ __launch_bounds__(64) void loss_final(
    const float* __restrict__ mid, float* __restrict__ out)
{
    const int lane = threadIdx.x;
    float acc[NPAD];
#pragma unroll
    for (int k = 0; k < NPAD; ++k) acc[k] = 0.f;
    if (lane < NMID) {
        const float* row = mid + lane * NPAD;
        const float4 r0 = ld4(row);     const float4 r1 = ld4(row + 4);
        const float4 r2 = ld4(row + 8); const float4 r3 = ld4(row + 12);
        acc[0] = r0.x;  acc[1] = r0.y;  acc[2] = r0.z;  acc[3] = r0.w;
        acc[4] = r1.x;  acc[5] = r1.y;  acc[6] = r1.z;  acc[7] = r1.w;
        acc[8] = r2.x;  acc[9] = r2.y;  acc[10] = r2.z; acc[11] = r2.w;
        acc[12] = r3.x; acc[13] = r3.y; acc[14] = r3.z; acc[15] = r3.w;
    }
#pragma unroll
    for (int k = 0; k < NACC; ++k) {
        for (int o = 32; o > 0; o >>= 1) acc[k] += __shfl_down(acc[k], o, 64);
    }
    if (lane == 0) {
        const float EPS = 1e-8f;
        // acc[0..3] are 3*M, 3*Mx, 3*My, 3*Mz (triple-counted)
        float loss = (acc[4] + acc[5]) / (acc[0] + EPS);   // W_MAE=1, W_MSE=1
        loss += 0.1f   * (acc[7] / (acc[1] + EPS) + acc[8] / (acc[2] + EPS)
                        + acc[9] / (acc[3] + EPS));
        loss += 0.002f * (acc[10] / (acc[1] + EPS) + acc[11] / (acc[2] + EPS)
                        + acc[12] / (acc[3] + EPS));
        const float inv3 = 12582912.f - acc[0];  // 3*(B*D*H*W) - 3*M
        loss += 0.15f * acc[6] / (inv3 + EPS);
        out[0] = loss;
    }
}

extern "C" void kernel_launch(void* const* d_in, const int* in_sizes, int n_in,
                              void* d_out, int out_size, void* d_ws, size_t ws_size,
                              hipStream_t stream) {
    const float* pred   = (const float*)d_in[0];
    const float* target = (const float*)d_in[1];
    const float* mask   = (const float*)d_in[2];
    float* out      = (float*)d_out;
    float* partials = (float*)d_ws;                       // 12288*16 floats
    float* mid      = partials + NBLOCKS * NPAD;          // 48*16 floats

    loss_main<<<NBLOCKS, 256, 0, stream>>>(pred, target, mask, partials);
    loss_mid<<<NMID, 256, 0, stream>>>(partials, mid);
    loss_final<<<1, 64, 0, stream>>>(mid, out);
}

// Round 7
// 153.565 us; speedup vs baseline: 1.3690x; 1.0270x over previous
//
#include <hip/hip_runtime.h>

// CompositeLoss: fused masked reduction over (2,3,128,128,128).
// R7: D-walk with register-carried previous plane. Thread owns (b,dc,h,w4),
// walks 8 d-planes; d-neighbor terms come from carried registers instead of
// global re-reads. In-thread channels (mask read once, not 3x). Evidence
// (R3 vs R6): time ~ total cache-line requests; this cuts cache-side bytes
// from ~380 MB (3x re-read) to ~263 MB (2x: self + h-neighbor, 1.125 d-seam).
// 13 partial sums (padded to 16 per block row in d_ws):
//  0:M 1:Mx(d) 2:My(h) 3:Mz(w)  4:Smae 5:Smse 6:Sbg
//  7:Sgx 8:Sgy 9:Sgz  10:Stx 11:Sty 12:Stz
#define NACC 13
#define NPAD 16
#define NBLOCKS 512   // 2*16*128*32 threads / 256

__device__ __forceinline__ float4 ld4(const float* p) {
    return *reinterpret_cast<const float4*>(p);
}

struct Plane { float4 m; float4 p[3]; float4 t[3]; };

// Loads plane d (self + h-neighbor + w-boundary scalars), accumulates all
// single-plane terms (M, My, Mz, mae, mse, bg, H-dir, W-dir), and returns
// the raw self values for the D-carry.
__device__ __forceinline__ void self_terms(
    const float* __restrict__ pred, const float* __restrict__ target,
    const float* __restrict__ mask, int mi, int pi0,
    bool hh, bool hw, float* acc, Plane& out)
{
    const float4 z4 = make_float4(0.f, 0.f, 0.f, 0.f);
    const float4 m0 = ld4(mask + mi);
    const float4 mh = hh ? ld4(mask + mi + 128) : z4;
    const float m4w = hw ? mask[mi + 4] : 0.f;
    out.m = m0;

    const float mz0 = fminf(m0.x, m0.y), mz1 = fminf(m0.y, m0.z),
                mz2 = fminf(m0.z, m0.w), mz3 = fminf(m0.w, m4w);
    const float my0 = fminf(m0.x, mh.x), my1 = fminf(m0.y, mh.y),
                my2 = fminf(m0.z, mh.z), my3 = fminf(m0.w, mh.w);

    acc[0] += m0.x + m0.y + m0.z + m0.w;
    acc[2] += my0 + my1 + my2 + my3;
    acc[3] += mz0 + mz1 + mz2 + mz3;

#pragma unroll
    for (int c = 0; c < 3; ++c) {
        const int pi = pi0 + c * 2097152;
        const float4 p0 = ld4(pred + pi);
        const float4 t0 = ld4(target + pi);
        const float4 ph = hh ? ld4(pred + pi + 128)   : z4;
        const float4 th = hh ? ld4(target + pi + 128) : z4;
        const float p4 = hw ? pred[pi + 4]   : 0.f;
        const float t4 = hw ? target[pi + 4] : 0.f;
        out.p[c] = p0; out.t[c] = t0;

        const float e0x = p0.x - t0.x, e0y = p0.y - t0.y,
                    e0z = p0.z - t0.z, e0w = p0.w - t0.w;
        const float e4  = p4 - t4;

        acc[4] += fabsf(e0x)*m0.x + fabsf(e0y)*m0.y
                + fabsf(e0z)*m0.z + fabsf(e0w)*m0.w;
        acc[5] += e0x*e0x*m0.x + e0y*e0y*m0.y
                + e0z*e0z*m0.z + e0w*e0w*m0.w;
        acc[6] += fabsf(p0.x)*(1.f-m0.x) + fabsf(p0.y)*(1.f-m0.y)
                + fabsf(p0.z)*(1.f-m0.z) + fabsf(p0.w)*(1.f-m0.w);

        // W direction (reference dz)
        acc[9]  += fabsf(e0y-e0x)*mz0 + fabsf(e0z-e0y)*mz1
                 + fabsf(e0w-e0z)*mz2 + fabsf(e4 -e0w)*mz3;
        acc[12] += fabsf(p0.y-p0.x)*mz0 + fabsf(p0.z-p0.y)*mz1
                 + fabsf(p0.w-p0.z)*mz2 + fabsf(p4  -p0.w)*mz3;

        // H direction (reference dy)
        acc[8]  += fabsf((ph.x-th.x)-e0x)*my0 + fabsf((ph.y-th.y)-e0y)*my1
                 + fabsf((ph.z-th.z)-e0z)*my2 + fabsf((ph.w-th.w)-e0w)*my3;
        acc[11] += fabsf(ph.x-p0.x)*my0 + fabsf(ph.y-p0.y)*my1
                 + fabsf(ph.z-p0.z)*my2 + fabsf(ph.w-p0.w)*my3;
    }
}

__global__ __launch_bounds__(256) void loss_main(
    const float* __restrict__ pred, const float* __restrict__ target,
    const float* __restrict__ mask, float* __restrict__ partials)
{
    float acc[NACC];
#pragma unroll
    for (int k = 0; k < NACC; ++k) acc[k] = 0.f;

    const int g  = blockIdx.x * 256 + threadIdx.x;
    const int w4 = g & 31;
    const int h  = (g >> 5) & 127;
    const int dc = (g >> 12) & 15;   // d-chunk: planes 8*dc .. 8*dc+8
    const int b  = g >> 16;
    const int w  = w4 << 2;
    const int sp = h * 128 + w;
    const int mbase = b * 2097152;
    const int pbase = b * 6291456;
    const bool hw = w4 < 31, hh = h < 127;
    const int d0 = dc << 3;

    // ---- init: load carry plane d0; dc==0 also owns plane 0's self terms
    Plane prev;
    if (dc == 0) {
        self_terms(pred, target, mask, mbase + sp, pbase + sp, hh, hw, acc, prev);
    } else {
        const int mi = mbase + d0 * 16384 + sp;
        const int pi0 = pbase + d0 * 16384 + sp;
        prev.m = ld4(mask + mi);
#pragma unroll
        for (int c = 0; c < 3; ++c) {
            prev.p[c] = ld4(pred + pi0 + c * 2097152);
            prev.t[c] = ld4(target + pi0 + c * 2097152);
        }
    }

    // ---- walk d = d0+1 .. d0+8 (chunk 15 stops at 127)
#pragma unroll 1
    for (int s = 1; s <= 8; ++s) {
        const int d = d0 + s;
        if (d > 127) break;
        const int mi  = mbase + d * 16384 + sp;
        const int pi0 = pbase + d * 16384 + sp;

        Plane cur;
        self_terms(pred, target, mask, mi, pi0, hh, hw, acc, cur);

        // D direction (reference dx): pair (d-1, d) from carried registers
        const float mx0 = fminf(prev.m.x, cur.m.x),
                    mx1 = fminf(prev.m.y, cur.m.y),
                    mx2 = fminf(prev.m.z, cur.m.z),
                    mx3 = fminf(prev.m.w, cur.m.w);
        acc[1] += mx0 + mx1 + mx2 + mx3;
#pragma unroll
        for (int c = 0; c < 3; ++c) {
            const float ecx = cur.p[c].x - cur.t[c].x,
                        ecy = cur.p[c].y - cur.t[c].y,
                        ecz = cur.p[c].z - cur.t[c].z,
                        ecw = cur.p[c].w - cur.t[c].w;
            const float epx = prev.p[c].x - prev.t[c].x,
                        epy = prev.p[c].y - prev.t[c].y,
                        epz = prev.p[c].z - prev.t[c].z,
                        epw = prev.p[c].w - prev.t[c].w;
            acc[7]  += fabsf(ecx-epx)*mx0 + fabsf(ecy-epy)*mx1
                     + fabsf(ecz-epz)*mx2 + fabsf(ecw-epw)*mx3;
            acc[10] += fabsf(cur.p[c].x-prev.p[c].x)*mx0
                     + fabsf(cur.p[c].y-prev.p[c].y)*mx1
                     + fabsf(cur.p[c].z-prev.p[c].z)*mx2
                     + fabsf(cur.p[c].w-prev.p[c].w)*mx3;
        }
        prev = cur;
    }

    // wave (64) shuffle reduce -> LDS -> padded per-block row [block][16]
    const int lane = threadIdx.x & 63;
    const int wave = threadIdx.x >> 6;
    __shared__ float red[4][NACC];
#pragma unroll
    for (int k = 0; k < NACC; ++k) {
        float v = acc[k];
        for (int o = 32; o > 0; o >>= 1) v += __shfl_down(v, o, 64);
        if (lane == 0) red[wave][k] = v;
    }
    __syncthreads();
    if (threadIdx.x < NPAD) {
        const int k = threadIdx.x;
        const float v = (k < NACC)
            ? red[0][k] + red[1][k] + red[2][k] + red[3][k] : 0.f;
        partials[blockIdx.x * NPAD + k] = v;  // d_ws is poisoned: write all 16
    }
}

// Single block folds 512 rows: thread t reads rows t and t+256
// (8 independent float4 -> latency overlapped), reduce + scalar epilogue.
__global__ __launch_bounds__(256) void loss_final(
    const float* __restrict__ partials, float* __restrict__ out)
{
    const float* rowA = partials + threadIdx.x * NPAD;
    const float* rowB = partials + (threadIdx.x + 256) * NPAD;
    const float4 a0 = ld4(rowA), a1 = ld4(rowA + 4),
                 a2 = ld4(rowA + 8), a3 = ld4(rowA + 12);
    const float4 b0 = ld4(rowB), b1 = ld4(rowB + 4),
                 b2 = ld4(rowB + 8), b3 = ld4(rowB + 12);
    float acc[NPAD] = {
        a0.x+b0.x, a0.y+b0.y, a0.z+b0.z, a0.w+b0.w,
        a1.x+b1.x, a1.y+b1.y, a1.z+b1.z, a1.w+b1.w,
        a2.x+b2.x, a2.y+b2.y, a2.z+b2.z, a2.w+b2.w,
        a3.x+b3.x, a3.y+b3.y, a3.z+b3.z, a3.w+b3.w};

    const int lane = threadIdx.x & 63;
    const int wave = threadIdx.x >> 6;
    __shared__ float red[4][NPAD];
#pragma unroll
    for (int k = 0; k < NACC; ++k) {
        float v = acc[k];
        for (int o = 32; o > 0; o >>= 1) v += __shfl_down(v, o, 64);
        if (lane == 0) red[wave][k] = v;
    }
    __syncthreads();
    if (threadIdx.x == 0) {
        float a[NACC];
#pragma unroll
        for (int k = 0; k < NACC; ++k)
            a[k] = red[0][k] + red[1][k] + red[2][k] + red[3][k];
        const float EPS = 1e-8f;
        const float M = a[0], Mx = a[1], My = a[2], Mz = a[3];
        float loss = (a[4] + a[5]) / (3.f * M + EPS);   // W_MAE=1, W_MSE=1
        loss += 0.1f   * (a[7] / (3.f*Mx + EPS) + a[8] / (3.f*My + EPS)
                        + a[9] / (3.f*Mz + EPS));
        loss += 0.002f * (a[10] / (3.f*Mx + EPS) + a[11] / (3.f*My + EPS)
                        + a[12] / (3.f*Mz + EPS));
        const float inv = 4194304.f - M;  // B*D*H*W - M
        loss += 0.15f * a[6] / (3.f * inv + EPS);
        out[0] = loss;
    }
}

extern "C" void kernel_launch(void* const* d_in, const int* in_sizes, int n_in,
                              void* d_out, int out_size, void* d_ws, size_t ws_size,
                              hipStream_t stream) {
    const float* pred   = (const float*)d_in[0];
    const float* target = (const float*)d_in[1];
    const float* mask   = (const float*)d_in[2];
    float* out      = (float*)d_out;
    float* partials = (float*)d_ws;  // NBLOCKS * NPAD floats = 32 KiB

    loss_main<<<NBLOCKS, 256, 0, stream>>>(pred, target, mask, partials);
    loss_final<<<1, 256, 0, stream>>>(partials, out);
}

// Round 8
// 145.430 us; speedup vs baseline: 1.4456x; 1.0559x over previous
//
#include <hip/hip_runtime.h>

// CompositeLoss: fused masked reduction over (2,3,128,128,128).
// R8: R3's main body (best measured: 41.3 us, FETCH 64 MB) with 128-thread
// blocks (8192 blocks). Group mapping g->(b,d,h,w4) is bit-identical to R3;
// only block granularity changes. Probe: R3's measured residency was 2.4
// waves/SIMD (occ 30%) with 4-wave blocks; 2-wave blocks let the CU pack up
// to 16 WGs -> higher residency -> more outstanding L2-miss lines.
// Tail = proven two-level tree (mid 32x256, final 1 wave), ~3 us.
// 13 partial sums (padded to 16 per block row in d_ws):
//  0:M 1:Mx(d) 2:My(h) 3:Mz(w)  4:Smae 5:Smse 6:Sbg
//  7:Sgx 8:Sgy 9:Sgz  10:Stx 11:Sty 12:Stz
#define NACC 13
#define NPAD 16
#define NBLOCKS 8192   // 2^20 threads / 128
#define NMID 32        // 8192 / 256

__device__ __forceinline__ float4 ld4(const float* p) {
    return *reinterpret_cast<const float4*>(p);
}

__global__ __launch_bounds__(128) void loss_main(
    const float* __restrict__ pred, const float* __restrict__ target,
    const float* __restrict__ mask, float* __restrict__ partials)
{
    float acc[NACC];
#pragma unroll
    for (int k = 0; k < NACC; ++k) acc[k] = 0.f;

    const float4 z4 = make_float4(0.f, 0.f, 0.f, 0.f);

    // one group per thread: group = (b, d, h, w4); mapping identical to R3
    const int g  = blockIdx.x * 128 + threadIdx.x;
    const int w4 = g & 31;
    const int h  = (g >> 5) & 127;
    const int d  = (g >> 12) & 127;
    const int b  = g >> 19;
    const int w  = w4 << 2;
    const int mb  = b * 2097152 + d * 16384 + h * 128 + w; // mask index
    const int pb0 = b * 6291456 + d * 16384 + h * 128 + w; // pred/target base
    const bool hw = w4 < 31, hh = h < 127, hd = d < 127;

    const float4 m0  = ld4(mask + mb);
    const float  m4w = hw ? mask[mb + 4] : 0.f;
    const float4 mh  = hh ? ld4(mask + mb + 128)   : z4;
    const float4 md  = hd ? ld4(mask + mb + 16384) : z4;

    // pairwise mins (binary mask -> AND); zero-filled neighbors kill OOB terms
    const float mz0 = fminf(m0.x, m0.y), mz1 = fminf(m0.y, m0.z),
                mz2 = fminf(m0.z, m0.w), mz3 = fminf(m0.w, m4w);
    const float my0 = fminf(m0.x, mh.x), my1 = fminf(m0.y, mh.y),
                my2 = fminf(m0.z, mh.z), my3 = fminf(m0.w, mh.w);
    const float mx0 = fminf(m0.x, md.x), mx1 = fminf(m0.y, md.y),
                mx2 = fminf(m0.z, md.z), mx3 = fminf(m0.w, md.w);

    acc[0] = m0.x + m0.y + m0.z + m0.w;
    acc[1] = mx0 + mx1 + mx2 + mx3;
    acc[2] = my0 + my1 + my2 + my3;
    acc[3] = mz0 + mz1 + mz2 + mz3;

#pragma unroll
    for (int c = 0; c < 3; ++c) {
        const int pb = pb0 + c * 2097152;
        const float4 p0 = ld4(pred + pb);
        const float4 t0 = ld4(target + pb);
        float p4 = 0.f, t4 = 0.f;
        if (hw) { p4 = pred[pb + 4]; t4 = target[pb + 4]; }
        const float4 ph = hh ? ld4(pred + pb + 128)     : z4;
        const float4 th = hh ? ld4(target + pb + 128)   : z4;
        const float4 pd = hd ? ld4(pred + pb + 16384)   : z4;
        const float4 td = hd ? ld4(target + pb + 16384) : z4;

        const float e0x = p0.x - t0.x, e0y = p0.y - t0.y,
                    e0z = p0.z - t0.z, e0w = p0.w - t0.w;
        const float e4  = p4 - t4;

        acc[4] += fabsf(e0x)*m0.x + fabsf(e0y)*m0.y
                + fabsf(e0z)*m0.z + fabsf(e0w)*m0.w;
        acc[5] += e0x*e0x*m0.x + e0y*e0y*m0.y
                + e0z*e0z*m0.z + e0w*e0w*m0.w;
        acc[6] += fabsf(p0.x)*(1.f-m0.x) + fabsf(p0.y)*(1.f-m0.y)
                + fabsf(p0.z)*(1.f-m0.z) + fabsf(p0.w)*(1.f-m0.w);

        // W direction (reference dz)
        acc[9]  += fabsf(e0y-e0x)*mz0 + fabsf(e0z-e0y)*mz1
                 + fabsf(e0w-e0z)*mz2 + fabsf(e4 -e0w)*mz3;
        acc[12] += fabsf(p0.y-p0.x)*mz0 + fabsf(p0.z-p0.y)*mz1
                 + fabsf(p0.w-p0.z)*mz2 + fabsf(p4  -p0.w)*mz3;

        // H direction (reference dy)
        acc[8]  += fabsf((ph.x-th.x)-e0x)*my0 + fabsf((ph.y-th.y)-e0y)*my1
                 + fabsf((ph.z-th.z)-e0z)*my2 + fabsf((ph.w-th.w)-e0w)*my3;
        acc[11] += fabsf(ph.x-p0.x)*my0 + fabsf(ph.y-p0.y)*my1
                 + fabsf(ph.z-p0.z)*my2 + fabsf(ph.w-p0.w)*my3;

        // D direction (reference dx)
        acc[7]  += fabsf((pd.x-td.x)-e0x)*mx0 + fabsf((pd.y-td.y)-e0y)*mx1
                 + fabsf((pd.z-td.z)-e0z)*mx2 + fabsf((pd.w-td.w)-e0w)*mx3;
        acc[10] += fabsf(pd.x-p0.x)*mx0 + fabsf(pd.y-p0.y)*mx1
                 + fabsf(pd.z-p0.z)*mx2 + fabsf(pd.w-p0.w)*mx3;
    }

    // wave (64) shuffle reduce -> LDS -> padded per-block row [block][16]
    const int lane = threadIdx.x & 63;
    const int wave = threadIdx.x >> 6;   // 0..1
    __shared__ float red[2][NACC];
#pragma unroll
    for (int k = 0; k < NACC; ++k) {
        float v = acc[k];
        for (int o = 32; o > 0; o >>= 1) v += __shfl_down(v, o, 64);
        if (lane == 0) red[wave][k] = v;
    }
    __syncthreads();
    if (threadIdx.x < NPAD) {
        const int k = threadIdx.x;
        const float v = (k < NACC) ? red[0][k] + red[1][k] : 0.f;
        partials[blockIdx.x * NPAD + k] = v;  // d_ws is poisoned: write all 16
    }
}

// Level 1: 32 blocks x 256 threads; thread r reads row r (4 independent
// float4), block-reduces 256 rows -> 1 row.
__global__ __launch_bounds__(256) void loss_mid(
    const float* __restrict__ partials, float* __restrict__ mid)
{
    const int r = blockIdx.x * 256 + threadIdx.x;   // exactly covers 8192
    const float* row = partials + r * NPAD;
    const float4 r0 = ld4(row);     const float4 r1 = ld4(row + 4);
    const float4 r2 = ld4(row + 8); const float4 r3 = ld4(row + 12);
    float acc[NPAD] = {r0.x, r0.y, r0.z, r0.w, r1.x, r1.y, r1.z, r1.w,
                       r2.x, r2.y, r2.z, r2.w, r3.x, r3.y, r3.z, r3.w};

    const int lane = threadIdx.x & 63;
    const int wave = threadIdx.x >> 6;
    __shared__ float red[4][NPAD];
#pragma unroll
    for (int k = 0; k < NPAD; ++k) {
        float v = acc[k];
        for (int o = 32; o > 0; o >>= 1) v += __shfl_down(v, o, 64);
        if (lane == 0) red[wave][k] = v;
    }
    __syncthreads();
    if (threadIdx.x < NPAD) {
        const int k = threadIdx.x;
        mid[blockIdx.x * NPAD + k] =
            red[0][k] + red[1][k] + red[2][k] + red[3][k];
    }
}

// Level 2: one wave; lane l reads mid row l (32 rows), shuffle-reduce,
// lane 0 does the scalar epilogue.
__global__ __launch_bounds__(64) void loss_final(
    const float* __restrict__ mid, float* __restrict__ out)
{
    const int lane = threadIdx.x;
    float acc[NPAD];
#pragma unroll
    for (int k = 0; k < NPAD; ++k) acc[k] = 0.f;
    if (lane < NMID) {
        const float* row = mid + lane * NPAD;
        const float4 r0 = ld4(row);     const float4 r1 = ld4(row + 4);
        const float4 r2 = ld4(row + 8); const float4 r3 = ld4(row + 12);
        acc[0] = r0.x;  acc[1] = r0.y;  acc[2] = r0.z;  acc[3] = r0.w;
        acc[4] = r1.x;  acc[5] = r1.y;  acc[6] = r1.z;  acc[7] = r1.w;
        acc[8] = r2.x;  acc[9] = r2.y;  acc[10] = r2.z; acc[11] = r2.w;
        acc[12] = r3.x; acc[13] = r3.y; acc[14] = r3.z; acc[15] = r3.w;
    }
#pragma unroll
    for (int k = 0; k < NACC; ++k) {
        for (int o = 32; o > 0; o >>= 1) acc[k] += __shfl_down(acc[k], o, 64);
    }
    if (lane == 0) {
        const float EPS = 1e-8f;
        const float M = acc[0], Mx = acc[1], My = acc[2], Mz = acc[3];
        float loss = (acc[4] + acc[5]) / (3.f * M + EPS);   // W_MAE=1, W_MSE=1
        loss += 0.1f   * (acc[7] / (3.f*Mx + EPS) + acc[8] / (3.f*My + EPS)
                        + acc[9] / (3.f*Mz + EPS));
        loss += 0.002f * (acc[10] / (3.f*Mx + EPS) + acc[11] / (3.f*My + EPS)
                        + acc[12] / (3.f*Mz + EPS));
        const float inv = 4194304.f - M;  // B*D*H*W - M
        loss += 0.15f * acc[6] / (3.f * inv + EPS);
        out[0] = loss;
    }
}

extern "C" void kernel_launch(void* const* d_in, const int* in_sizes, int n_in,
                              void* d_out, int out_size, void* d_ws, size_t ws_size,
                              hipStream_t stream) {
    const float* pred   = (const float*)d_in[0];
    const float* target = (const float*)d_in[1];
    const float* mask   = (const float*)d_in[2];
    float* out      = (float*)d_out;
    float* partials = (float*)d_ws;                 // 8192*16 floats = 512 KiB
    float* mid      = partials + NBLOCKS * NPAD;    // 32*16 floats

    loss_main<<<NBLOCKS, 128, 0, stream>>>(pred, target, mask, partials);
    loss_mid<<<NMID, 256, 0, stream>>>(partials, mid);
    loss_final<<<1, 64, 0, stream>>>(mid, out);
}